// Round 3
// baseline (322.915 us; speedup 1.0000x reference)
//
#include <hip/hip_runtime.h>
#include <stdint.h>

// RandomSaltPepper: out = where(mask, color, imgs)
//   imgs: (64, 3, 512, 512) f32
//   mask  = uniform(k1, (B,1,H,W)) < 0.5     -> per-(b,h,w), shared over C
//   idx   = randint(k2, (B,1,H,W), 0, 2); color = idx==0 ? 1.0 : 0.0
//   k1,k2 = split(key(42)); randint internally splits k2 again and uses
//   lower_bits = bits(split(k2)[1]) & 1 (span=2 -> multiplier 0).
//
// Exact JAX Threefry-2x32 (partitionable) — verified absmax=0.0 in R2.
// R3: 4 pixels/thread + float4 I/O (4x fewer vmem instrs, 8 indep PRNG chains).

constexpr int B = 64, C = 3, H = 512, W = 512;
constexpr uint32_t HW   = (uint32_t)H * W;        // 262144
constexpr uint32_t NPIX = (uint32_t)B * HW;       // 16777216
constexpr uint32_t CHW  = (uint32_t)C * HW;
constexpr uint32_t HW4  = HW / 4;                 // float4 stride between channels

#define ROTL32(x, r) (((x) << (r)) | ((x) >> (32 - (r))))

__host__ __device__ __forceinline__ void tf2x32(uint32_t k0, uint32_t k1,
                                                uint32_t x0, uint32_t x1,
                                                uint32_t* o0, uint32_t* o1) {
  const uint32_t ks0 = k0, ks1 = k1, ks2 = k0 ^ k1 ^ 0x1BD11BDAu;
  x0 += ks0; x1 += ks1;
#define TF_R4(ra, rb, rc, rd)                      \
  x0 += x1; x1 = ROTL32(x1, ra); x1 ^= x0;         \
  x0 += x1; x1 = ROTL32(x1, rb); x1 ^= x0;         \
  x0 += x1; x1 = ROTL32(x1, rc); x1 ^= x0;         \
  x0 += x1; x1 = ROTL32(x1, rd); x1 ^= x0;
  TF_R4(13, 15, 26, 6);  x0 += ks1; x1 += ks2 + 1u;
  TF_R4(17, 29, 16, 24); x0 += ks2; x1 += ks0 + 2u;
  TF_R4(13, 15, 26, 6);  x0 += ks0; x1 += ks1 + 3u;
  TF_R4(17, 29, 16, 24); x0 += ks1; x1 += ks2 + 4u;
  TF_R4(13, 15, 26, 6);  x0 += ks2; x1 += ks0 + 5u;
#undef TF_R4
  *o0 = x0; *o1 = x1;
}

// 32-bit random word at flat index j: fold both halves of threefry(key, 0, j)
__device__ __forceinline__ uint32_t rand_word(uint32_t ka, uint32_t kb, uint32_t j) {
  uint32_t o0, o1;
  tf2x32(ka, kb, 0u, j, &o0, &o1);
  return o0 ^ o1;
}

__global__ __launch_bounds__(256) void RandomSaltPepper_9380208574641_kernel(
    const float4* __restrict__ in, float4* __restrict__ out,
    uint32_t mka, uint32_t mkb, uint32_t cka, uint32_t ckb) {
  const uint32_t t  = blockIdx.x * 256u + threadIdx.x;  // pixel-quad index
  const uint32_t j0 = t * 4u;                            // first pixel of quad

  // quad never crosses a batch boundary (HW % 4 == 0)
  const uint32_t b   = j0 >> 18;                // j0 / HW
  const uint32_t hw  = j0 & (HW - 1u);          // j0 % HW
  const size_t base4 = ((size_t)b * CHW + hw) >> 2;  // float4 index

  // issue loads first so VMEM latency overlaps the PRNG chains
  float4 v0 = in[base4];
  float4 v1 = in[base4 + HW4];
  float4 v2 = in[base4 + 2u * HW4];

  bool  msk[4];
  float col[4];
#pragma unroll
  for (int q = 0; q < 4; ++q) {
    const uint32_t mb = rand_word(mka, mkb, j0 + (uint32_t)q);
    const uint32_t cb = rand_word(cka, ckb, j0 + (uint32_t)q);
    msk[q] = (mb & 0x80000000u) == 0u;          // uniform < 0.5
    col[q] = (cb & 1u) ? 0.0f : 1.0f;           // salt=1.0 / pepper=0.0
  }

  v0.x = msk[0] ? col[0] : v0.x;  v0.y = msk[1] ? col[1] : v0.y;
  v0.z = msk[2] ? col[2] : v0.z;  v0.w = msk[3] ? col[3] : v0.w;
  v1.x = msk[0] ? col[0] : v1.x;  v1.y = msk[1] ? col[1] : v1.y;
  v1.z = msk[2] ? col[2] : v1.z;  v1.w = msk[3] ? col[3] : v1.w;
  v2.x = msk[0] ? col[0] : v2.x;  v2.y = msk[1] ? col[1] : v2.y;
  v2.z = msk[2] ? col[2] : v2.z;  v2.w = msk[3] ? col[3] : v2.w;

  out[base4]           = v0;
  out[base4 + HW4]     = v1;
  out[base4 + 2u * HW4] = v2;
}

extern "C" void kernel_launch(void* const* d_in, const int* in_sizes, int n_in,
                              void* d_out, int out_size, void* d_ws, size_t ws_size,
                              hipStream_t stream) {
  const float4* imgs = (const float4*)d_in[0];
  float4* out = (float4*)d_out;

  // Host-side key derivation (deterministic, identical every call):
  //   k1, k2 = split(key(42)); color_key = split(k2)[1]
  const uint32_t pk0 = 0u, pk1 = 42u;
  uint32_t k1a, k1b, k2a, k2b, cka, ckb;
  // foldlike split: subkey i of split(key) = threefry(key, hi=0, lo=i)
  tf2x32(pk0, pk1, 0u, 0u, &k1a, &k1b);   // k1 (mask key)
  tf2x32(pk0, pk1, 0u, 1u, &k2a, &k2b);   // k2
  tf2x32(k2a, k2b, 0u, 1u, &cka, &ckb);   // split(k2)[1] -> lower_bits key

  const int threads = 256;
  const int blocks = (int)(NPIX / 4u / (uint32_t)threads);  // 16384
  RandomSaltPepper_9380208574641_kernel<<<blocks, threads, 0, stream>>>(
      imgs, out, k1a, k1b, cka, ckb);
}